// Round 8
// baseline (186.144 us; speedup 1.0000x reference)
//
#include <hip/hip_runtime.h>
#include <hip/hip_bf16.h>

// ---------------------------------------------------------------------------
// BehaviorSpecificPFF: token-routed 4-expert FFN.
//   y[tok] = relu(x[tok] @ W1[g] + B1[g]) @ W2[g] + B2[g],  g = b_seq[tok]-1
//   b_seq==0 -> zeros.
// Round 8: r7 coalesced staging (8 x 128B lines per wave-instr) + r5-verified
// 2-phase double-buffer (STAGE(next) -> COMPUTE(cur) -> vmcnt(0) -> barrier).
// r5's 2-phase null is explained: staging was transaction-bound then; r7
// removed that. Also: vectorized 64x64 W-transpose (float4 loads, 16B stores).
// ---------------------------------------------------------------------------

typedef short s16x8 __attribute__((ext_vector_type(8)));
typedef float f32x4 __attribute__((ext_vector_type(4)));

#define NTOK   16384
#define HDIM   512
#define FDIM   2048
#define NEXP   4

// ---- header layout (ints) in ws ----
// [0..3] counts  [4..7] cursors  [8..12] token offsets ([12]=total)
// [13..17] gemm1 tile bases ([17]=total)  [18..22] gemm2 tile bases

__global__ void k_init_cvt(const float* __restrict__ x,
                           const int* __restrict__ b_seq,
                           __hip_bfloat16* __restrict__ xb,
                           float4* __restrict__ out, int n4,
                           int* __restrict__ hdr, float4* __restrict__ zp) {
  if (blockIdx.x == 0 && threadIdx.x < 32) hdr[threadIdx.x] = 0;
  float4 z; z.x = z.y = z.z = z.w = 0.f;
  int zb = (int)blockIdx.x - 1;
  if (zb >= 0 && zb < 2) zp[zb * 256 + threadIdx.x] = z;  // 8KB zero slab
  union { __hip_bfloat16 b[4]; uint2 u; } t;
  for (int i = blockIdx.x * blockDim.x + threadIdx.x; i < n4;
       i += gridDim.x * blockDim.x) {
    // non-pad out rows are fully rewritten by GEMM2 every call; only padding
    // rows need zeros (out float4-row token = i>>7).
    if (b_seq[i >> 7] == 0) out[i] = z;
    float4 v = ((const float4*)x)[i];
    t.b[0] = __float2bfloat16(v.x);
    t.b[1] = __float2bfloat16(v.y);
    t.b[2] = __float2bfloat16(v.z);
    t.b[3] = __float2bfloat16(v.w);
    ((uint2*)xb)[i] = t.u;
  }
}

__global__ void k_count_scan(const int4* __restrict__ b4,
                             int* __restrict__ hdr) {
  __shared__ int cnt[4];
  if (threadIdx.x < 4) cnt[threadIdx.x] = 0;
  __syncthreads();
  int c0 = 0, c1 = 0, c2 = 0, c3 = 0;
  for (int i = threadIdx.x; i < NTOK / 4; i += 1024) {
    int4 v = b4[i];
    c0 += (v.x == 1) + (v.y == 1) + (v.z == 1) + (v.w == 1);
    c1 += (v.x == 2) + (v.y == 2) + (v.z == 2) + (v.w == 2);
    c2 += (v.x == 3) + (v.y == 3) + (v.z == 3) + (v.w == 3);
    c3 += (v.x == 4) + (v.y == 4) + (v.z == 4) + (v.w == 4);
  }
  if (c0) atomicAdd(&cnt[0], c0);
  if (c1) atomicAdd(&cnt[1], c1);
  if (c2) atomicAdd(&cnt[2], c2);
  if (c3) atomicAdd(&cnt[3], c3);
  __syncthreads();
  if (threadIdx.x == 0) {
    int off = 0, b1 = 0, b2 = 0;
    for (int g = 0; g < 4; ++g) {
      int c = cnt[g];
      hdr[g] = c;
      hdr[8 + g] = off;
      hdr[4 + g] = off;   // cursor
      hdr[13 + g] = b1;
      hdr[18 + g] = b2;
      int mt = (c + 127) >> 7;   // 128-row m-tiles
      off += c;
      b1 += mt * (FDIM / 128);   // 16 n-tiles
      b2 += mt * (HDIM / 128);   // 4 n-tiles
    }
    hdr[12] = off; hdr[17] = b1; hdr[22] = b2;
  }
}

// LDS-aggregated fill: one global atomic per (block, expert).
__global__ void k_fill(const int* __restrict__ b_seq, int* __restrict__ hdr,
                       int* __restrict__ perm) {
  __shared__ int lcnt[4], base[4];
  const int tid = threadIdx.x;
  if (tid < 4) lcnt[tid] = 0;
  __syncthreads();
  const int i = blockIdx.x * 256 + tid;
  const int g = b_seq[i];
  int r = -1;
  if (g > 0) r = atomicAdd(&lcnt[g - 1], 1);
  __syncthreads();
  if (tid < 4) {
    int c = lcnt[tid];
    base[tid] = c ? atomicAdd(&hdr[4 + tid], c) : 0;
  }
  __syncthreads();
  if (g > 0) perm[base[g - 1] + r] = i;
}

// dst[g][c][r] = bf16(src[g][r][c]); 64x64 tiles, 256 threads.
// Load: float4 per thread (256B/row-wave); store: 2 x 16B bf16, 128B/row.
// grid (C/64, R/64, NEXP)
__global__ void k_transpose_cvt(const float* __restrict__ src,
                                __hip_bfloat16* __restrict__ dst, int R, int C) {
  __shared__ float tile[64][69];   // pad 69 (odd): conflict-free col reads
  const int g = blockIdx.z;
  const float* S = src + (size_t)g * R * C;
  __hip_bfloat16* D = dst + (size_t)g * R * C;
  const int c0 = blockIdx.x << 6, r0 = blockIdx.y << 6;
  const int t = threadIdx.x;
  const int lr = t >> 4, lc = (t & 15) << 2;
#pragma unroll
  for (int p = 0; p < 4; ++p) {
    float4 v = *(const float4*)(S + (size_t)(r0 + lr + p * 16) * C + c0 + lc);
    float* tr = &tile[lr + p * 16][lc];
    tr[0] = v.x; tr[1] = v.y; tr[2] = v.z; tr[3] = v.w;
  }
  __syncthreads();
  const int c = t >> 2, rq = t & 3;    // 4 lanes cover one D-row's 64 r's
  union { __hip_bfloat16 b[8]; s16x8 v; } u0, u1;
#pragma unroll
  for (int j = 0; j < 8; ++j) {
    u0.b[j] = __float2bfloat16(tile[rq * 16 + j][c]);
    u1.b[j] = __float2bfloat16(tile[rq * 16 + 8 + j][c]);
  }
  __hip_bfloat16* drow = D + (size_t)(c0 + c) * R + r0 + (rq << 4);
  *(s16x8*)drow = u0.v;
  *(s16x8*)(drow + 8) = u1.v;
}

__device__ __forceinline__ f32x4 mfma16(s16x8 a, s16x8 b, f32x4 c) {
  asm("v_mfma_f32_16x16x32_bf16 %0, %1, %2, %0" : "+v"(c) : "v"(a), "v"(b));
  return c;
}

__device__ __forceinline__ void gload16(const void* g, void* lds) {
  __builtin_amdgcn_global_load_lds(
      (const __attribute__((address_space(1))) unsigned int*)g,
      (__attribute__((address_space(3))) unsigned int*)lds, 16, 0, 0);
}

// Grouped GEMM, 128x128 tile, BK=64, 4 waves each computing [64,64].
// Coalesced staging (r7): instr i of wave wv covers rows wv*32+i*8..+7, lane
// l -> row +(l>>3), chunk l&7 -> 8 aligned 128B lines per wave-instruction.
// Source chunk pre-swizzled within its line (chunk ^= row&7); LDS linear
// [row][chunk]; fragment reads XOR the same swizzle.
// 2-phase dbuf (r5): STAGE(next) -> COMPUTE(cur) -> vmcnt(0) -> s_barrier.
// End-of-iter barrier separates COMPUTE(s) reads from STAGE(s+1) overwrite.
// MODE 1: A = xb gathered via perm (K=512), B = W1t; relu+bias; C staged in
//         LDS (stride 272, overlays dbuf) -> coalesced 128B stores to Hws.
// MODE 2: A = Hws packed (K=2048), B = W2t; +bias; fp32 scatter to d_out.
template <int MODE>
__global__ __launch_bounds__(256, 2)
void k_gemm(const int* __restrict__ hdr, const int* __restrict__ perm,
            const __hip_bfloat16* __restrict__ Asrc,
            const __hip_bfloat16* __restrict__ Bsrc,
            const float* __restrict__ bias,
            const __hip_bfloat16* __restrict__ zp,
            __hip_bfloat16* __restrict__ Hout, float* __restrict__ Yout) {
  constexpr int K    = (MODE == 1) ? HDIM : FDIM;
  constexpr int NS   = K / 64;                    // K-steps
  constexpr int NT   = (MODE == 1) ? FDIM / 128 : HDIM / 128;
  constexpr int NF   = (MODE == 1) ? FDIM : HDIM;
  constexpr int CPX  = (MODE == 1) ? 264 : 66;    // grid/8 (worst-case tiles)
  const int* tb = hdr + ((MODE == 1) ? 13 : 18);

  __shared__ __align__(16) char LDS[65536];
  char* As = LDS;            // 2 x 16KB dbuf: [128 rows][64 bf16]
  char* Bs = LDS + 32768;    // 2 x 16KB dbuf

  const int bid = blockIdx.x;
  const int w = (bid & 7) * CPX + (bid >> 3);     // XCD-contiguous tiles
  if (w >= tb[4]) return;

  const int tid = threadIdx.x, lane = tid & 63, wv = tid >> 6;
  const int wm = (wv >> 1) << 6, wn = (wv & 1) << 6;
  const int l15 = lane & 15, lq = lane >> 4;
  const int rsub = lane >> 3, c8 = lane & 7;      // staging: row-sub, chunk
  const int csw = (c8 ^ rsub) << 3;               // swizzled chunk (elems)

  int g = 0;
  while (tb[g + 1] <= w) ++g;
  const int local = w - tb[g];
  const int mt = local / NT, nt = local % NT;
  const int cnt = hdr[g], off = hdr[8 + g];
  int nrows = cnt - (mt << 7);
  nrows = nrows > 128 ? 128 : nrows;

  // per-instruction source pointers (advance 64 elems per K-step)
  const __hip_bfloat16* ap[4];
  const __hip_bfloat16* bp[4];
#pragma unroll
  for (int i = 0; i < 4; ++i) {
    const int r = (wv << 5) + (i << 3) + rsub;
    if (MODE == 1) {
      if (r < nrows) {
        const int tok = perm[off + (mt << 7) + r];
        ap[i] = Asrc + (size_t)tok * K + csw;
      } else {
        ap[i] = zp + csw;   // zero slab (walks K=512 -> ~1.1KB < 8KB slab)
      }
    } else {
      // OOB rows read in-bounds finite garbage from Hws; masked at store.
      ap[i] = Asrc + (size_t)(off + (mt << 7) + r) * K + csw;
    }
    bp[i] = Bsrc + ((size_t)g * NF + (nt << 7) + r) * K + csw;
  }

  f32x4 acc[4][4];
  const f32x4 fz = {0.f, 0.f, 0.f, 0.f};
#pragma unroll
  for (int m = 0; m < 4; ++m)
#pragma unroll
    for (int n = 0; n < 4; ++n) acc[m][n] = fz;

  auto STAGE = [&](int bo) {
#pragma unroll
    for (int i = 0; i < 4; ++i) {
      const int lo = bo + (wv << 12) + (i << 10);  // wave-uniform LDS base
      gload16(ap[i], As + lo);
      gload16(bp[i], Bs + lo);
      ap[i] += 64;
      bp[i] += 64;
    }
  };
  auto COMPUTE = [&](int bo) {
#pragma unroll
    for (int kk = 0; kk < 2; ++kk) {
      const int kb = (kk << 6) + (lq << 4);
      s16x8 a[4], b[4];
#pragma unroll
      for (int m = 0; m < 4; ++m) {
        const int row = wm + (m << 4) + l15;
        a[m] = *(const s16x8*)(As + bo + (row << 7) + (kb ^ ((row & 7) << 4)));
      }
#pragma unroll
      for (int n = 0; n < 4; ++n) {
        const int row = wn + (n << 4) + l15;
        b[n] = *(const s16x8*)(Bs + bo + (row << 7) + (kb ^ ((row & 7) << 4)));
      }
#pragma unroll
      for (int m = 0; m < 4; ++m)
#pragma unroll
        for (int n = 0; n < 4; ++n)
          acc[m][n] = mfma16(a[kk == 0 ? m : m], b[n], acc[m][n]);
    }
  };

  // prologue: stage K-step 0, drain, sync
  STAGE(0);
  asm volatile("s_waitcnt vmcnt(0)" ::: "memory");
  __builtin_amdgcn_s_barrier();
  asm volatile("" ::: "memory");

  int bo = 0;
  for (int s = 0; s < NS; ++s) {
    if (s + 1 < NS) STAGE(bo ^ 16384);  // issue next-step loads (other buf)
    COMPUTE(bo);                         // overlaps with in-flight staging
    asm volatile("s_waitcnt vmcnt(0)" ::: "memory");  // next buf landed
    __builtin_amdgcn_s_barrier();        // also: all reads of bo done
    asm volatile("" ::: "memory");
    bo ^= 16384;
  }
  asm volatile("s_nop 7\ns_nop 7\ns_nop 7");      // MFMA->VALU hazard guard

  const int rq = lq << 2;
  if constexpr (MODE == 1) {
    // stage relu(acc+bias) in LDS (stride 272 spreads banks; overlays dbuf
    // after the final barrier), then coalesced 128B half-row stores.
#pragma unroll
    for (int n = 0; n < 4; ++n) {
      const int col = wn + (n << 4) + l15;
      const float bv = bias[g * NF + (nt << 7) + col];
#pragma unroll
      for (int m = 0; m < 4; ++m)
#pragma unroll
        for (int j = 0; j < 4; ++j) {
          const int row = wm + (m << 4) + rq + j;
          float v = acc[m][n][j] + bv;
          v = v > 0.f ? v : 0.f;
          *(__hip_bfloat16*)(LDS + row * 272 + col * 2) = __float2bfloat16(v);
        }
    }
    __syncthreads();
    const int r = tid >> 1, hf = tid & 1;
    if (r < nrows) {
      const char* src = LDS + r * 272 + hf * 128;
      char* dst = (char*)(Hout + ((size_t)(off + (mt << 7) + r) << 11) +
                          (nt << 7)) + hf * 128;
#pragma unroll
      for (int q = 0; q < 8; ++q)
        *(s16x8*)(dst + q * 16) = *(const s16x8*)(src + q * 16);
    }
  } else {
#pragma unroll
    for (int n = 0; n < 4; ++n) {
      const int ncol = (nt << 7) + wn + (n << 4) + l15;
      const float bv = bias[g * NF + ncol];
#pragma unroll
      for (int m = 0; m < 4; ++m)
#pragma unroll
        for (int j = 0; j < 4; ++j) {
          const int rl = wm + (m << 4) + rq + j;
          if (rl < nrows) {
            const int tok = perm[off + (mt << 7) + rl];
            Yout[((size_t)tok << 9) + ncol] = acc[m][n][j] + bv;
          }
        }
    }
  }
}

extern "C" void kernel_launch(void* const* d_in, const int* in_sizes, int n_in,
                              void* d_out, int out_size, void* d_ws,
                              size_t ws_size, hipStream_t stream) {
  const float* x    = (const float*)d_in[0];
  const int* b_seq  = (const int*)d_in[1];
  const float* W1   = (const float*)d_in[2];
  const float* B1   = (const float*)d_in[3];
  const float* W2   = (const float*)d_in[4];
  const float* B2   = (const float*)d_in[5];
  float* out        = (float*)d_out;

  char* ws = (char*)d_ws;
  int* hdr  = (int*)ws;                         // 1 KB header
  int* perm = (int*)(ws + 1024);                // 64 KB
  __hip_bfloat16* zp = (__hip_bfloat16*)(ws + 66560);       // 8 KB zeros
  __hip_bfloat16* xb = zp + 4096;
  __hip_bfloat16* W1t = xb + (size_t)NTOK * HDIM;           // [4][2048][512]
  __hip_bfloat16* W2t = W1t + (size_t)NEXP * FDIM * HDIM;   // [4][512][2048]
  __hip_bfloat16* Hws = W2t + (size_t)NEXP * HDIM * FDIM;   // [16384][2048]

  const int n4 = NTOK * HDIM / 4;

  k_init_cvt<<<2048, 256, 0, stream>>>(x, b_seq, xb, (float4*)out, n4, hdr,
                                       (float4*)zp);
  k_count_scan<<<1, 1024, 0, stream>>>((const int4*)b_seq, hdr);
  k_fill<<<NTOK / 256, 256, 0, stream>>>(b_seq, hdr, perm);
  k_transpose_cvt<<<dim3(FDIM / 64, HDIM / 64, NEXP), 256, 0, stream>>>(
      W1, W1t, HDIM, FDIM);
  k_transpose_cvt<<<dim3(HDIM / 64, FDIM / 64, NEXP), 256, 0, stream>>>(
      W2, W2t, FDIM, HDIM);
  // grids cover worst-case tile counts: <=132 m-tiles -> 2112 / 528
  k_gemm<1><<<2112, 256, 0, stream>>>(hdr, perm, xb, W1t, B1, zp, Hws, nullptr);
  k_gemm<2><<<528, 256, 0, stream>>>(hdr, perm, Hws, W2t, B2, zp, nullptr, out);
}

// Round 9
// 170.305 us; speedup vs baseline: 1.0930x; 1.0930x over previous
//
#include <hip/hip_runtime.h>
#include <hip/hip_bf16.h>

// ---------------------------------------------------------------------------
// BehaviorSpecificPFF: token-routed 4-expert FFN.
//   y[tok] = relu(x[tok] @ W1[g] + B1[g]) @ W2[g] + B2[g],  g = b_seq[tok]-1
//   b_seq==0 -> zeros.
// Round 9: r7 skeleton (single 32KB buffer, __syncthreads, coalesced
// global_load_lds staging) + runtime-bijective XCD swizzle over the ACTUAL
// tile count (fixes XCD-7 starvation from worst-case-sized compile-time
// swizzle) + LDS shrunk to exactly 32KB (C-stage overlaid via row-XOR).
// 2-phase dbuf is falsified twice (r5 null, r8 regression) - not retried.
// ---------------------------------------------------------------------------

typedef short s16x8 __attribute__((ext_vector_type(8)));
typedef float f32x4 __attribute__((ext_vector_type(4)));

#define NTOK   16384
#define HDIM   512
#define FDIM   2048
#define NEXP   4

// ---- header layout (ints) in ws ----
// [0..3] counts  [4..7] cursors  [8..12] token offsets ([12]=total)
// [13..17] gemm1 tile bases ([17]=total)  [18..22] gemm2 tile bases

__global__ void k_init_cvt(const float* __restrict__ x,
                           const int* __restrict__ b_seq,
                           __hip_bfloat16* __restrict__ xb,
                           float4* __restrict__ out, int n4,
                           int* __restrict__ hdr, float4* __restrict__ zp) {
  if (blockIdx.x == 0 && threadIdx.x < 32) hdr[threadIdx.x] = 0;
  float4 z; z.x = z.y = z.z = z.w = 0.f;
  int zb = (int)blockIdx.x - 1;
  if (zb >= 0 && zb < 2) zp[zb * 256 + threadIdx.x] = z;  // 8KB zero slab
  union { __hip_bfloat16 b[4]; uint2 u; } t;
  for (int i = blockIdx.x * blockDim.x + threadIdx.x; i < n4;
       i += gridDim.x * blockDim.x) {
    // non-pad out rows are fully rewritten by GEMM2 every call; only padding
    // rows need zeros (out float4-row token = i>>7).
    if (b_seq[i >> 7] == 0) out[i] = z;
    float4 v = ((const float4*)x)[i];
    t.b[0] = __float2bfloat16(v.x);
    t.b[1] = __float2bfloat16(v.y);
    t.b[2] = __float2bfloat16(v.z);
    t.b[3] = __float2bfloat16(v.w);
    ((uint2*)xb)[i] = t.u;
  }
}

__global__ void k_count_scan(const int4* __restrict__ b4,
                             int* __restrict__ hdr) {
  __shared__ int cnt[4];
  if (threadIdx.x < 4) cnt[threadIdx.x] = 0;
  __syncthreads();
  int c0 = 0, c1 = 0, c2 = 0, c3 = 0;
  for (int i = threadIdx.x; i < NTOK / 4; i += 1024) {
    int4 v = b4[i];
    c0 += (v.x == 1) + (v.y == 1) + (v.z == 1) + (v.w == 1);
    c1 += (v.x == 2) + (v.y == 2) + (v.z == 2) + (v.w == 2);
    c2 += (v.x == 3) + (v.y == 3) + (v.z == 3) + (v.w == 3);
    c3 += (v.x == 4) + (v.y == 4) + (v.z == 4) + (v.w == 4);
  }
  if (c0) atomicAdd(&cnt[0], c0);
  if (c1) atomicAdd(&cnt[1], c1);
  if (c2) atomicAdd(&cnt[2], c2);
  if (c3) atomicAdd(&cnt[3], c3);
  __syncthreads();
  if (threadIdx.x == 0) {
    int off = 0, b1 = 0, b2 = 0;
    for (int g = 0; g < 4; ++g) {
      int c = cnt[g];
      hdr[g] = c;
      hdr[8 + g] = off;
      hdr[4 + g] = off;   // cursor
      hdr[13 + g] = b1;
      hdr[18 + g] = b2;
      int mt = (c + 127) >> 7;   // 128-row m-tiles
      off += c;
      b1 += mt * (FDIM / 128);   // 16 n-tiles
      b2 += mt * (HDIM / 128);   // 4 n-tiles
    }
    hdr[12] = off; hdr[17] = b1; hdr[22] = b2;
  }
}

// LDS-aggregated fill: one global atomic per (block, expert).
__global__ void k_fill(const int* __restrict__ b_seq, int* __restrict__ hdr,
                       int* __restrict__ perm) {
  __shared__ int lcnt[4], base[4];
  const int tid = threadIdx.x;
  if (tid < 4) lcnt[tid] = 0;
  __syncthreads();
  const int i = blockIdx.x * 256 + tid;
  const int g = b_seq[i];
  int r = -1;
  if (g > 0) r = atomicAdd(&lcnt[g - 1], 1);
  __syncthreads();
  if (tid < 4) {
    int c = lcnt[tid];
    base[tid] = c ? atomicAdd(&hdr[4 + tid], c) : 0;
  }
  __syncthreads();
  if (g > 0) perm[base[g - 1] + r] = i;
}

// dst[g][c][r] = bf16(src[g][r][c]); 64x64 tiles, 256 threads.
// Load: float4 per thread; store: 2 x 16B bf16, 128B per transposed row.
// grid (C/64, R/64, NEXP)
__global__ void k_transpose_cvt(const float* __restrict__ src,
                                __hip_bfloat16* __restrict__ dst, int R, int C) {
  __shared__ float tile[64][69];   // pad 69: conflict-free col reads
  const int g = blockIdx.z;
  const float* S = src + (size_t)g * R * C;
  __hip_bfloat16* D = dst + (size_t)g * R * C;
  const int c0 = blockIdx.x << 6, r0 = blockIdx.y << 6;
  const int t = threadIdx.x;
  const int lr = t >> 4, lc = (t & 15) << 2;
#pragma unroll
  for (int p = 0; p < 4; ++p) {
    float4 v = *(const float4*)(S + (size_t)(r0 + lr + p * 16) * C + c0 + lc);
    float* tr = &tile[lr + p * 16][lc];
    tr[0] = v.x; tr[1] = v.y; tr[2] = v.z; tr[3] = v.w;
  }
  __syncthreads();
  const int c = t >> 2, rq = t & 3;
  union { __hip_bfloat16 b[8]; s16x8 v; } u0, u1;
#pragma unroll
  for (int j = 0; j < 8; ++j) {
    u0.b[j] = __float2bfloat16(tile[rq * 16 + j][c]);
    u1.b[j] = __float2bfloat16(tile[rq * 16 + 8 + j][c]);
  }
  __hip_bfloat16* drow = D + (size_t)(c0 + c) * R + r0 + (rq << 4);
  *(s16x8*)drow = u0.v;
  *(s16x8*)(drow + 8) = u1.v;
}

__device__ __forceinline__ f32x4 mfma16(s16x8 a, s16x8 b, f32x4 c) {
  asm("v_mfma_f32_16x16x32_bf16 %0, %1, %2, %0" : "+v"(c) : "v"(a), "v"(b));
  return c;
}

__device__ __forceinline__ void gload16(const void* g, void* lds) {
  __builtin_amdgcn_global_load_lds(
      (const __attribute__((address_space(1))) unsigned int*)g,
      (__attribute__((address_space(3))) unsigned int*)lds, 16, 0, 0);
}

// Grouped GEMM, 128x128 tile, BK=64, 4 waves each computing [64,64].
// Coalesced staging (r7): instr i of wave wv covers rows wv*32+i*8..+7, lane
// l -> row +(l>>3), chunk l&7 -> 8 aligned 128B lines per wave-instruction.
// Source chunk pre-swizzled within its line (chunk ^= row&7); LDS linear
// [row][chunk]; fragment reads XOR the same swizzle.
// Tile distribution: grid-stride over [0,total) with a RUNTIME bijective
// XCD swizzle (m204) computed from the actual total, so active tiles spread
// over all 8 XCDs for any b_seq (fixes XCD-7 starvation of r7's
// worst-case-sized compile-time swizzle).
// MODE 1: A = xb gathered via perm (K=512), B = W1t; relu+bias; C staged in
//         LDS (row-XOR overlay of the 32KB A/B region) -> 128B stores to Hws.
// MODE 2: A = Hws packed (K=2048), B = W2t; +bias; fp32 scatter to d_out.
template <int MODE>
__global__ __launch_bounds__(256, 4)
void k_gemm(const int* __restrict__ hdr, const int* __restrict__ perm,
            const __hip_bfloat16* __restrict__ Asrc,
            const __hip_bfloat16* __restrict__ Bsrc,
            const float* __restrict__ bias,
            const __hip_bfloat16* __restrict__ zp,
            __hip_bfloat16* __restrict__ Hout, float* __restrict__ Yout) {
  constexpr int K    = (MODE == 1) ? HDIM : FDIM;
  constexpr int NS   = K / 64;                    // K-steps
  constexpr int NT   = (MODE == 1) ? FDIM / 128 : HDIM / 128;
  constexpr int NF   = (MODE == 1) ? FDIM : HDIM;
  const int* tb = hdr + ((MODE == 1) ? 13 : 18);
  const int total = tb[4];
  const int qc = total >> 3, rc = total & 7;      // runtime swizzle params

  __shared__ __align__(16) char LDS[32768];
  char* As = LDS;            // 16KB: [128 rows][64 bf16]
  char* Bs = LDS + 16384;    // 16KB

  const int tid = threadIdx.x, lane = tid & 63, wv = tid >> 6;
  const int wm = (wv >> 1) << 6, wn = (wv & 1) << 6;
  const int l15 = lane & 15, lq = lane >> 4;
  const int rsub = lane >> 3, c8 = lane & 7;      // staging: row-sub, chunk
  const int csw = (c8 ^ rsub) << 3;               // swizzled chunk (elems)

  for (int idx = blockIdx.x; idx < total; idx += gridDim.x) {
    // m204 bijective XCD swizzle on the actual tile count
    const int xcd = idx & 7;
    const int base = (xcd < rc) ? xcd * (qc + 1) : rc * (qc + 1) + (xcd - rc) * qc;
    const int w = base + (idx >> 3);

    int g = 0;
    while (tb[g + 1] <= w) ++g;
    const int local = w - tb[g];
    const int mt = local / NT, nt = local % NT;
    const int cnt = hdr[g], off = hdr[8 + g];
    int nrows = cnt - (mt << 7);
    nrows = nrows > 128 ? 128 : nrows;

    // per-instruction source pointers (advance 64 elems per K-step)
    const __hip_bfloat16* ap[4];
    const __hip_bfloat16* bp[4];
#pragma unroll
    for (int i = 0; i < 4; ++i) {
      const int r = (wv << 5) + (i << 3) + rsub;
      if (MODE == 1) {
        if (r < nrows) {
          const int tok = perm[off + (mt << 7) + r];
          ap[i] = Asrc + (size_t)tok * K + csw;
        } else {
          ap[i] = zp + csw;   // zero slab (walks K=512 -> ~1.1KB < 8KB slab)
        }
      } else {
        // OOB rows read in-bounds finite garbage from Hws; masked at store.
        ap[i] = Asrc + (size_t)(off + (mt << 7) + r) * K + csw;
      }
      bp[i] = Bsrc + ((size_t)g * NF + (nt << 7) + r) * K + csw;
    }

    f32x4 acc[4][4];
    const f32x4 fz = {0.f, 0.f, 0.f, 0.f};
#pragma unroll
    for (int m = 0; m < 4; ++m)
#pragma unroll
      for (int n = 0; n < 4; ++n) acc[m][n] = fz;

    for (int s = 0; s < NS; ++s) {
#pragma unroll
      for (int i = 0; i < 4; ++i) {
        const int lo = (wv << 12) + (i << 10);    // wave-uniform LDS base
        gload16(ap[i], As + lo);
        gload16(bp[i], Bs + lo);
        ap[i] += 64;
        bp[i] += 64;
      }
      __syncthreads();                            // staging visible
#pragma unroll
      for (int kk = 0; kk < 2; ++kk) {
        const int kb = (kk << 6) + (lq << 4);
        s16x8 a[4], b[4];
#pragma unroll
        for (int m = 0; m < 4; ++m) {
          const int row = wm + (m << 4) + l15;
          a[m] = *(const s16x8*)(As + (row << 7) + (kb ^ ((row & 7) << 4)));
        }
#pragma unroll
        for (int n = 0; n < 4; ++n) {
          const int row = wn + (n << 4) + l15;
          b[n] = *(const s16x8*)(Bs + (row << 7) + (kb ^ ((row & 7) << 4)));
        }
#pragma unroll
        for (int m = 0; m < 4; ++m)
#pragma unroll
          for (int n = 0; n < 4; ++n)
            acc[m][n] = mfma16(a[m], b[n], acc[m][n]);
      }
      __syncthreads();                            // reads done before restage
    }
    asm volatile("s_nop 7\ns_nop 7\ns_nop 7");    // MFMA->VALU hazard guard

    const int rq = lq << 2;
    if constexpr (MODE == 1) {
      // C-stage overlays the 32KB A/B region: byte = row*256 +
      // ((col*2) ^ ((row&7)<<4)) -- bijective within each row's 256B.
#pragma unroll
      for (int n = 0; n < 4; ++n) {
        const int col = wn + (n << 4) + l15;
        const float bv = bias[g * NF + (nt << 7) + col];
#pragma unroll
        for (int m = 0; m < 4; ++m)
#pragma unroll
          for (int j = 0; j < 4; ++j) {
            const int row = wm + (m << 4) + rq + j;
            float v = acc[m][n][j] + bv;
            v = v > 0.f ? v : 0.f;
            *(__hip_bfloat16*)(LDS + row * 256 + ((col << 1) ^ ((row & 7) << 4))) =
                __float2bfloat16(v);
          }
      }
      __syncthreads();
      const int r = tid >> 1, hf = tid & 1;
      if (r < nrows) {
        char* dst = (char*)(Hout + ((size_t)(off + (mt << 7) + r) << 11) +
                            (nt << 7)) + hf * 128;
        const char* srow = LDS + r * 256;
        const int sx = (r & 7) << 4;
#pragma unroll
        for (int q = 0; q < 8; ++q)
          *(s16x8*)(dst + q * 16) =
              *(const s16x8*)(srow + (((hf << 7) + (q << 4)) ^ sx));
      }
      __syncthreads();   // C-stage reads done before next tile's STAGE
    } else {
#pragma unroll
      for (int n = 0; n < 4; ++n) {
        const int ncol = (nt << 7) + wn + (n << 4) + l15;
        const float bv = bias[g * NF + ncol];
#pragma unroll
        for (int m = 0; m < 4; ++m)
#pragma unroll
          for (int j = 0; j < 4; ++j) {
            const int rl = wm + (m << 4) + rq + j;
            if (rl < nrows) {
              const int tok = perm[off + (mt << 7) + rl];
              Yout[((size_t)tok << 9) + ncol] = acc[m][n][j] + bv;
            }
          }
      }
    }
  }
}

extern "C" void kernel_launch(void* const* d_in, const int* in_sizes, int n_in,
                              void* d_out, int out_size, void* d_ws,
                              size_t ws_size, hipStream_t stream) {
  const float* x    = (const float*)d_in[0];
  const int* b_seq  = (const int*)d_in[1];
  const float* W1   = (const float*)d_in[2];
  const float* B1   = (const float*)d_in[3];
  const float* W2   = (const float*)d_in[4];
  const float* B2   = (const float*)d_in[5];
  float* out        = (float*)d_out;

  char* ws = (char*)d_ws;
  int* hdr  = (int*)ws;                         // 1 KB header
  int* perm = (int*)(ws + 1024);                // 64 KB
  __hip_bfloat16* zp = (__hip_bfloat16*)(ws + 66560);       // 8 KB zeros
  __hip_bfloat16* xb = zp + 4096;
  __hip_bfloat16* W1t = xb + (size_t)NTOK * HDIM;           // [4][2048][512]
  __hip_bfloat16* W2t = W1t + (size_t)NEXP * FDIM * HDIM;   // [4][512][2048]
  __hip_bfloat16* Hws = W2t + (size_t)NEXP * HDIM * FDIM;   // [16384][2048]

  const int n4 = NTOK * HDIM / 4;

  k_init_cvt<<<2048, 256, 0, stream>>>(x, b_seq, xb, (float4*)out, n4, hdr,
                                       (float4*)zp);
  k_count_scan<<<1, 1024, 0, stream>>>((const int4*)b_seq, hdr);
  k_fill<<<NTOK / 256, 256, 0, stream>>>(b_seq, hdr, perm);
  k_transpose_cvt<<<dim3(FDIM / 64, HDIM / 64, NEXP), 256, 0, stream>>>(
      W1, W1t, HDIM, FDIM);
  k_transpose_cvt<<<dim3(HDIM / 64, FDIM / 64, NEXP), 256, 0, stream>>>(
      W2, W2t, FDIM, HDIM);
  // grid-stride covers worst-case tiles (2112 / 1040); swizzle is runtime
  k_gemm<1><<<2048, 256, 0, stream>>>(hdr, perm, xb, W1t, B1, zp, Hws, nullptr);
  k_gemm<2><<<512, 256, 0, stream>>>(hdr, perm, Hws, W2t, B2, zp, nullptr, out);
}

// Round 10
// 131.337 us; speedup vs baseline: 1.4173x; 1.2967x over previous
//
#include <hip/hip_runtime.h>
#include <hip/hip_bf16.h>

// ---------------------------------------------------------------------------
// BehaviorSpecificPFF: token-routed 4-expert FFN.
//   y[tok] = relu(x[tok] @ W1[g] + B1[g]) @ W2[g] + B2[g],  g = b_seq[tok]-1
//   b_seq==0 -> zeros.
// Round 10: r7 GEMM body EXACTLY (single 32KB A/B buffer, 2-barrier K-loop,
// stride-272 C-stage, LDS 34816, launch_bounds(256,2), 1 tile/block) with a
// single change: runtime-bijective (m204) XCD swizzle over the ACTUAL tile
// count, activating all 8 XCDs (r7's worst-case chunks idled XCD 7).
// r9's residency increase (5 blocks/CU) is reverted: FETCH tripled and perf
// followed traffic -- at this footprint ~2 blocks/CU + hot L2 wins.
// ---------------------------------------------------------------------------

typedef short s16x8 __attribute__((ext_vector_type(8)));
typedef float f32x4 __attribute__((ext_vector_type(4)));

#define NTOK   16384
#define HDIM   512
#define FDIM   2048
#define NEXP   4

// ---- header layout (ints) in ws ----
// [0..3] counts  [4..7] cursors  [8..12] token offsets ([12]=total)
// [13..17] gemm1 tile bases ([17]=total)  [18..22] gemm2 tile bases

__global__ void k_init_cvt(const float* __restrict__ x,
                           const int* __restrict__ b_seq,
                           __hip_bfloat16* __restrict__ xb,
                           float4* __restrict__ out, int n4,
                           int* __restrict__ hdr, float4* __restrict__ zp) {
  if (blockIdx.x == 0 && threadIdx.x < 32) hdr[threadIdx.x] = 0;
  float4 z; z.x = z.y = z.z = z.w = 0.f;
  int zb = (int)blockIdx.x - 1;
  if (zb >= 0 && zb < 2) zp[zb * 256 + threadIdx.x] = z;  // 8KB zero slab
  union { __hip_bfloat16 b[4]; uint2 u; } t;
  for (int i = blockIdx.x * blockDim.x + threadIdx.x; i < n4;
       i += gridDim.x * blockDim.x) {
    // non-pad out rows are fully rewritten by GEMM2 every call; only padding
    // rows need zeros (out float4-row token = i>>7).
    if (b_seq[i >> 7] == 0) out[i] = z;
    float4 v = ((const float4*)x)[i];
    t.b[0] = __float2bfloat16(v.x);
    t.b[1] = __float2bfloat16(v.y);
    t.b[2] = __float2bfloat16(v.z);
    t.b[3] = __float2bfloat16(v.w);
    ((uint2*)xb)[i] = t.u;
  }
}

__global__ void k_count_scan(const int4* __restrict__ b4,
                             int* __restrict__ hdr) {
  __shared__ int cnt[4];
  if (threadIdx.x < 4) cnt[threadIdx.x] = 0;
  __syncthreads();
  int c0 = 0, c1 = 0, c2 = 0, c3 = 0;
  for (int i = threadIdx.x; i < NTOK / 4; i += 1024) {
    int4 v = b4[i];
    c0 += (v.x == 1) + (v.y == 1) + (v.z == 1) + (v.w == 1);
    c1 += (v.x == 2) + (v.y == 2) + (v.z == 2) + (v.w == 2);
    c2 += (v.x == 3) + (v.y == 3) + (v.z == 3) + (v.w == 3);
    c3 += (v.x == 4) + (v.y == 4) + (v.z == 4) + (v.w == 4);
  }
  if (c0) atomicAdd(&cnt[0], c0);
  if (c1) atomicAdd(&cnt[1], c1);
  if (c2) atomicAdd(&cnt[2], c2);
  if (c3) atomicAdd(&cnt[3], c3);
  __syncthreads();
  if (threadIdx.x == 0) {
    int off = 0, b1 = 0, b2 = 0;
    for (int g = 0; g < 4; ++g) {
      int c = cnt[g];
      hdr[g] = c;
      hdr[8 + g] = off;
      hdr[4 + g] = off;   // cursor
      hdr[13 + g] = b1;
      hdr[18 + g] = b2;
      int mt = (c + 127) >> 7;   // 128-row m-tiles
      off += c;
      b1 += mt * (FDIM / 128);   // 16 n-tiles
      b2 += mt * (HDIM / 128);   // 4 n-tiles
    }
    hdr[12] = off; hdr[17] = b1; hdr[22] = b2;
  }
}

// LDS-aggregated fill: one global atomic per (block, expert).
__global__ void k_fill(const int* __restrict__ b_seq, int* __restrict__ hdr,
                       int* __restrict__ perm) {
  __shared__ int lcnt[4], base[4];
  const int tid = threadIdx.x;
  if (tid < 4) lcnt[tid] = 0;
  __syncthreads();
  const int i = blockIdx.x * 256 + tid;
  const int g = b_seq[i];
  int r = -1;
  if (g > 0) r = atomicAdd(&lcnt[g - 1], 1);
  __syncthreads();
  if (tid < 4) {
    int c = lcnt[tid];
    base[tid] = c ? atomicAdd(&hdr[4 + tid], c) : 0;
  }
  __syncthreads();
  if (g > 0) perm[base[g - 1] + r] = i;
}

// dst[g][c][r] = bf16(src[g][r][c]); 64x64 tiles, 256 threads.
// Load: float4 per thread; store: 2 x 16B bf16, 128B per transposed row.
// grid (C/64, R/64, NEXP)
__global__ void k_transpose_cvt(const float* __restrict__ src,
                                __hip_bfloat16* __restrict__ dst, int R, int C) {
  __shared__ float tile[64][69];   // pad 69: conflict-free col reads
  const int g = blockIdx.z;
  const float* S = src + (size_t)g * R * C;
  __hip_bfloat16* D = dst + (size_t)g * R * C;
  const int c0 = blockIdx.x << 6, r0 = blockIdx.y << 6;
  const int t = threadIdx.x;
  const int lr = t >> 4, lc = (t & 15) << 2;
#pragma unroll
  for (int p = 0; p < 4; ++p) {
    float4 v = *(const float4*)(S + (size_t)(r0 + lr + p * 16) * C + c0 + lc);
    float* tr = &tile[lr + p * 16][lc];
    tr[0] = v.x; tr[1] = v.y; tr[2] = v.z; tr[3] = v.w;
  }
  __syncthreads();
  const int c = t >> 2, rq = t & 3;
  union { __hip_bfloat16 b[8]; s16x8 v; } u0, u1;
#pragma unroll
  for (int j = 0; j < 8; ++j) {
    u0.b[j] = __float2bfloat16(tile[rq * 16 + j][c]);
    u1.b[j] = __float2bfloat16(tile[rq * 16 + 8 + j][c]);
  }
  __hip_bfloat16* drow = D + (size_t)(c0 + c) * R + r0 + (rq << 4);
  *(s16x8*)drow = u0.v;
  *(s16x8*)(drow + 8) = u1.v;
}

__device__ __forceinline__ f32x4 mfma16(s16x8 a, s16x8 b, f32x4 c) {
  asm("v_mfma_f32_16x16x32_bf16 %0, %1, %2, %0" : "+v"(c) : "v"(a), "v"(b));
  return c;
}

__device__ __forceinline__ void gload16(const void* g, void* lds) {
  __builtin_amdgcn_global_load_lds(
      (const __attribute__((address_space(1))) unsigned int*)g,
      (__attribute__((address_space(3))) unsigned int*)lds, 16, 0, 0);
}

// Grouped GEMM, 128x128 tile, BK=64, 4 waves each computing [64,64].
// Coalesced staging (r7): instr i of wave wv covers rows wv*32+i*8..+7, lane
// l -> row +(l>>3), chunk l&7 -> 8 aligned 128B lines per wave-instruction.
// Source chunk pre-swizzled within its line (chunk ^= row&7); LDS linear
// [row][chunk]; fragment reads XOR the same swizzle.
// Tile mapping: runtime-bijective m204 XCD swizzle over the actual total;
// one tile per block, early exit. Per-XCD w-ranges stay contiguous (A-tile
// and W-panel L2 reuse preserved) and all 8 XCDs are active for any b_seq.
// MODE 1: A = xb gathered via perm (K=512), B = W1t; relu+bias; C staged in
//         LDS (stride 272) -> coalesced 128B stores to packed Hws (bf16).
// MODE 2: A = Hws packed (K=2048), B = W2t; +bias; fp32 scatter to d_out.
template <int MODE>
__global__ __launch_bounds__(256, 2)
void k_gemm(const int* __restrict__ hdr, const int* __restrict__ perm,
            const __hip_bfloat16* __restrict__ Asrc,
            const __hip_bfloat16* __restrict__ Bsrc,
            const float* __restrict__ bias,
            const __hip_bfloat16* __restrict__ zp,
            __hip_bfloat16* __restrict__ Hout, float* __restrict__ Yout) {
  constexpr int K    = (MODE == 1) ? HDIM : FDIM;
  constexpr int NS   = K / 64;                    // K-steps
  constexpr int NT   = (MODE == 1) ? FDIM / 128 : HDIM / 128;
  constexpr int NF   = (MODE == 1) ? FDIM : HDIM;
  constexpr int LDSZ = (MODE == 1) ? 34816 : 32768;  // 128*272 C-stage
  const int* tb = hdr + ((MODE == 1) ? 13 : 18);
  const int total = tb[4];

  __shared__ __align__(16) char LDS[LDSZ];
  char* As = LDS;            // 16KB: [128 rows][64 bf16]
  char* Bs = LDS + 16384;    // 16KB

  const int idx = blockIdx.x;
  if (idx >= total) return;
  // m204 runtime-bijective XCD swizzle on the actual tile count
  const int qc = total >> 3, rc = total & 7;
  const int xcd = idx & 7;
  const int cbase = (xcd < rc) ? xcd * (qc + 1) : rc * (qc + 1) + (xcd - rc) * qc;
  const int w = cbase + (idx >> 3);

  const int tid = threadIdx.x, lane = tid & 63, wv = tid >> 6;
  const int wm = (wv >> 1) << 6, wn = (wv & 1) << 6;
  const int l15 = lane & 15, lq = lane >> 4;
  const int rsub = lane >> 3, c8 = lane & 7;      // staging: row-sub, chunk
  const int csw = (c8 ^ rsub) << 3;               // swizzled chunk (elems)

  int g = 0;
  while (tb[g + 1] <= w) ++g;
  const int local = w - tb[g];
  const int mt = local / NT, nt = local % NT;
  const int cnt = hdr[g], off = hdr[8 + g];
  int nrows = cnt - (mt << 7);
  nrows = nrows > 128 ? 128 : nrows;

  // per-instruction source pointers (advance 64 elems per K-step)
  const __hip_bfloat16* ap[4];
  const __hip_bfloat16* bp[4];
#pragma unroll
  for (int i = 0; i < 4; ++i) {
    const int r = (wv << 5) + (i << 3) + rsub;
    if (MODE == 1) {
      if (r < nrows) {
        const int tok = perm[off + (mt << 7) + r];
        ap[i] = Asrc + (size_t)tok * K + csw;
      } else {
        ap[i] = zp + csw;   // zero slab (walks K=512 -> ~1.1KB < 8KB slab)
      }
    } else {
      // OOB rows read in-bounds finite garbage from Hws; masked at store.
      ap[i] = Asrc + (size_t)(off + (mt << 7) + r) * K + csw;
    }
    bp[i] = Bsrc + ((size_t)g * NF + (nt << 7) + r) * K + csw;
  }

  f32x4 acc[4][4];
  const f32x4 fz = {0.f, 0.f, 0.f, 0.f};
#pragma unroll
  for (int m = 0; m < 4; ++m)
#pragma unroll
    for (int n = 0; n < 4; ++n) acc[m][n] = fz;

  for (int s = 0; s < NS; ++s) {
#pragma unroll
    for (int i = 0; i < 4; ++i) {
      const int lo = (wv << 12) + (i << 10);      // wave-uniform LDS base
      gload16(ap[i], As + lo);
      gload16(bp[i], Bs + lo);
      ap[i] += 64;
      bp[i] += 64;
    }
    __syncthreads();                              // staging visible
#pragma unroll
    for (int kk = 0; kk < 2; ++kk) {
      const int kb = (kk << 6) + (lq << 4);
      s16x8 a[4], b[4];
#pragma unroll
      for (int m = 0; m < 4; ++m) {
        const int row = wm + (m << 4) + l15;
        a[m] = *(const s16x8*)(As + (row << 7) + (kb ^ ((row & 7) << 4)));
      }
#pragma unroll
      for (int n = 0; n < 4; ++n) {
        const int row = wn + (n << 4) + l15;
        b[n] = *(const s16x8*)(Bs + (row << 7) + (kb ^ ((row & 7) << 4)));
      }
#pragma unroll
      for (int m = 0; m < 4; ++m)
#pragma unroll
        for (int n = 0; n < 4; ++n)
          acc[m][n] = mfma16(a[m], b[n], acc[m][n]);
    }
    __syncthreads();                              // reads done before restage
  }
  asm volatile("s_nop 7\ns_nop 7\ns_nop 7");      // MFMA->VALU hazard guard

  const int rq = lq << 2;
  if constexpr (MODE == 1) {
    // stage relu(acc+bias) in LDS (stride 272 spreads banks), then
    // coalesced 128B half-row stores.
#pragma unroll
    for (int n = 0; n < 4; ++n) {
      const int col = wn + (n << 4) + l15;
      const float bv = bias[g * NF + (nt << 7) + col];
#pragma unroll
      for (int m = 0; m < 4; ++m)
#pragma unroll
        for (int j = 0; j < 4; ++j) {
          const int row = wm + (m << 4) + rq + j;
          float v = acc[m][n][j] + bv;
          v = v > 0.f ? v : 0.f;
          *(__hip_bfloat16*)(LDS + row * 272 + col * 2) = __float2bfloat16(v);
        }
    }
    __syncthreads();
    const int r = tid >> 1, hf = tid & 1;
    if (r < nrows) {
      const char* src = LDS + r * 272 + hf * 128;
      char* dst = (char*)(Hout + ((size_t)(off + (mt << 7) + r) << 11) +
                          (nt << 7)) + hf * 128;
#pragma unroll
      for (int q = 0; q < 8; ++q)
        *(s16x8*)(dst + q * 16) = *(const s16x8*)(src + q * 16);
    }
  } else {
#pragma unroll
    for (int n = 0; n < 4; ++n) {
      const int ncol = (nt << 7) + wn + (n << 4) + l15;
      const float bv = bias[g * NF + ncol];
#pragma unroll
      for (int m = 0; m < 4; ++m)
#pragma unroll
        for (int j = 0; j < 4; ++j) {
          const int rl = wm + (m << 4) + rq + j;
          if (rl < nrows) {
            const int tok = perm[off + (mt << 7) + rl];
            Yout[((size_t)tok << 9) + ncol] = acc[m][n][j] + bv;
          }
        }
    }
  }
}

extern "C" void kernel_launch(void* const* d_in, const int* in_sizes, int n_in,
                              void* d_out, int out_size, void* d_ws,
                              size_t ws_size, hipStream_t stream) {
  const float* x    = (const float*)d_in[0];
  const int* b_seq  = (const int*)d_in[1];
  const float* W1   = (const float*)d_in[2];
  const float* B1   = (const float*)d_in[3];
  const float* W2   = (const float*)d_in[4];
  const float* B2   = (const float*)d_in[5];
  float* out        = (float*)d_out;

  char* ws = (char*)d_ws;
  int* hdr  = (int*)ws;                         // 1 KB header
  int* perm = (int*)(ws + 1024);                // 64 KB
  __hip_bfloat16* zp = (__hip_bfloat16*)(ws + 66560);       // 8 KB zeros
  __hip_bfloat16* xb = zp + 4096;
  __hip_bfloat16* W1t = xb + (size_t)NTOK * HDIM;           // [4][2048][512]
  __hip_bfloat16* W2t = W1t + (size_t)NEXP * FDIM * HDIM;   // [4][512][2048]
  __hip_bfloat16* Hws = W2t + (size_t)NEXP * HDIM * FDIM;   // [16384][2048]

  const int n4 = NTOK * HDIM / 4;

  k_init_cvt<<<2048, 256, 0, stream>>>(x, b_seq, xb, (float4*)out, n4, hdr,
                                       (float4*)zp);
  k_count_scan<<<1, 1024, 0, stream>>>((const int4*)b_seq, hdr);
  k_fill<<<NTOK / 256, 256, 0, stream>>>(b_seq, hdr, perm);
  k_transpose_cvt<<<dim3(FDIM / 64, HDIM / 64, NEXP), 256, 0, stream>>>(
      W1, W1t, HDIM, FDIM);
  k_transpose_cvt<<<dim3(HDIM / 64, FDIM / 64, NEXP), 256, 0, stream>>>(
      W2, W2t, FDIM, HDIM);
  // grids cover worst-case tile counts; blocks past the actual total exit
  k_gemm<1><<<2112, 256, 0, stream>>>(hdr, perm, xb, W1t, B1, zp, Hws, nullptr);
  k_gemm<2><<<528, 256, 0, stream>>>(hdr, perm, Hws, W2t, B2, zp, nullptr, out);
}